// Round 6
// baseline (524.856 us; speedup 1.0000x reference)
//
#include <hip/hip_runtime.h>
#include <math.h>

// WindowAttention: B=2048, C=256, H=8, d_k=32, wh=ww=7 -> L=49, nW=64.
// Reference reassigns v = k. Outputs: score (2048*256*49) then attn
// (2048*8*49*49), fp32, concatenated in d_out.
//
// MFMA design, R6: TWO waves cooperate on one (b,h) (128-thread block).
// Wave wv owns S row-tiles {2wv, 2wv+1} (acc 32 regs) and score c-tile wv
// (acc2 16 regs). Peak live state ~95 regs (R5: ~180) -> ~5 waves/SIMD by
// regs; shared 12.25 KiB LDS -> 12 blocks/CU -> ~20 waves/CU (2x R5).
//
// Counter-proven history: R2-R4 HBM amplification was SCRATCH SPILL from
// launch_bounds-forced VGPR caps (WRITE tracked the cap, not the store
// layout); R1/R5 show frag-scattered direct stores are clean when there is
// no spill. So attn/score are written DIRECTLY from registers here, and
// launch_bounds(128,4) leaves reg headroom (cap 128 > ~95 need).
//
//  phase1: S = Q^T K via mfma_f32_16x16x32_bf16 (M=N=49->64, K=32 exact),
//          RNE hi/lo bf16 split, 3 passes -> ~fp32 accuracy.
//  softmax on C-frag layout (col=lane&15, row=(lane>>4)*4+reg) via shfl_xor.
//  P staged to LDS as SEPARATE hi/lo bf16 planes (49 x 64 u16 each,
//          16B-slot XOR swizzle (s>>3)^(t&7)) -> phase-3 A-frags are direct
//          ds_read_b128, no unpack ALU. ONE __syncthreads (pack -> read).
//  phase3: score = K P^T; K2 loads issued pre-barrier to hide latency.
//  bias+mask pre-expanded into fragment order -> coalesced f32x4 loads.

#define LW 49
#define NH 8

typedef short s16x8 __attribute__((ext_vector_type(8)));
typedef float f32x4 __attribute__((ext_vector_type(4)));

union Frag { s16x8 v; unsigned short u[8]; };

__device__ __forceinline__ unsigned short f2bf(float x) {
    unsigned u = __float_as_uint(x);
    u += 0x7FFFu + ((u >> 16) & 1u);          // round-to-nearest-even
    return (unsigned short)(u >> 16);
}
__device__ __forceinline__ float bf2f(unsigned short h) {
    return __uint_as_float(((unsigned)h) << 16);
}
// RNE split: hi = bf16_rne(x); lo = bf16_rne(x - hi).
__device__ __forceinline__ void split8(const float* xf, Frag& hi, Frag& lo) {
    #pragma unroll
    for (int j = 0; j < 8; j++) {
        const unsigned short hb = f2bf(xf[j]);
        hi.u[j] = hb;
        lo.u[j] = f2bf(xf[j] - bf2f(hb));
    }
}

#define MFMA16(A, B, C) __builtin_amdgcn_mfma_f32_16x16x32_bf16((A), (B), (C), 0, 0, 0)

// ---------------- prep: bias & mask expanded into C-fragment order ----------
__global__ __launch_bounds__(256) void prep_frag_kernel(
    const float* __restrict__ mask, const float* __restrict__ table,
    const int* __restrict__ idx,
    float* __restrict__ biasF, float* __restrict__ maskF)
{
    const int i = blockIdx.x * 256 + threadIdx.x;
    const int NBF = 8 * 4096;        // 32768
    const int NMF = 64 * 4096;       // 262144
    if (i < NBF) {
        const int h = i >> 12, rem = i & 4095;
        const int gi = rem >> 8, lane = (rem >> 2) & 63, r = rem & 3;
        const int mt = gi >> 2, nt = gi & 3;
        const int t = mt * 16 + (lane >> 4) * 4 + r;
        const int s = nt * 16 + (lane & 15);
        biasF[i] = (t < LW && s < LW) ? table[idx[t * LW + s] * NH + h] : 0.f;
    } else if (i < NBF + NMF) {
        const int j = i - NBF;
        const int w2 = j >> 12, rem = j & 4095;
        const int gi = rem >> 8, lane = (rem >> 2) & 63, r = rem & 3;
        const int mt = gi >> 2, nt = gi & 3;
        const int t = mt * 16 + (lane >> 4) * 4 + r;
        const int s = nt * 16 + (lane & 15);
        maskF[j] = (t < LW && s < LW) ? mask[w2 * (LW * LW) + t * LW + s] : 0.f;
    }
}

// ---------------- main: 2 waves per (b,h) -----------------------------------
__global__ __launch_bounds__(128, 4) void wa_mfma_kernel(
    const float* __restrict__ q, const float* __restrict__ k,
    const float* __restrict__ biasF, const float* __restrict__ maskF,
    float* __restrict__ score_out, float* __restrict__ attn_out)
{
    // P planes: hi/lo bf16, 49 rows x 64 cols, 16B-slot XOR swizzle.
    __shared__ __align__(16) unsigned short sHi[LW * 64];   // 6272 B
    __shared__ __align__(16) unsigned short sLo[LW * 64];   // 6272 B

    const int wv   = __builtin_amdgcn_readfirstlane((int)(threadIdx.x >> 6));
    const int bh   = blockIdx.x;
    const int h    = bh & 7;
    const int w    = (bh >> 3) & 63;
    const int lane = threadIdx.x & 63;
    const int l15  = lane & 15;
    const int g4   = lane >> 4;

    const float* qp = q + (size_t)bh * (32 * LW);
    const float* kp = k + (size_t)bh * (32 * LW);

    // ---- A-frags: Q^T rows t for THIS wave's 2 row-tiles ----
    Frag Qh[2], Ql[2];
    #pragma unroll
    for (int mi = 0; mi < 2; mi++) {
        const int mtg = wv * 2 + mi;
        const int t   = mtg * 16 + l15;
        const int tc  = t < LW ? t : (LW - 1);         // clamp pad rows
        float xf[8];
        #pragma unroll
        for (int j = 0; j < 8; j++) xf[j] = qp[(g4 * 8 + j) * LW + tc];
        split8(xf, Qh[mi], Ql[mi]);
    }

    // ---- phase 1: S rows of this wave (3-pass split bf16) ----
    f32x4 acc[2][4];
    #pragma unroll
    for (int mi = 0; mi < 2; mi++)
        #pragma unroll
        for (int nt = 0; nt < 4; nt++)
            #pragma unroll
            for (int r = 0; r < 4; r++) acc[mi][nt][r] = 0.f;

    #pragma unroll
    for (int nt = 0; nt < 4; nt++) {
        const int s  = nt * 16 + l15;
        const int sc = s < LW ? s : (LW - 1);
        float xf[8];
        #pragma unroll
        for (int j = 0; j < 8; j++) xf[j] = kp[(g4 * 8 + j) * LW + sc];
        Frag Kh, Kl;
        split8(xf, Kh, Kl);
        #pragma unroll
        for (int mi = 0; mi < 2; mi++) {
            acc[mi][nt] = MFMA16(Qh[mi].v, Kh.v, acc[mi][nt]);
            acc[mi][nt] = MFMA16(Ql[mi].v, Kh.v, acc[mi][nt]);
            acc[mi][nt] = MFMA16(Qh[mi].v, Kl.v, acc[mi][nt]);
        }
    }

    // ---- scale + bias + mask (frag-ordered tables); pad cols -> -inf ----
    const float scale = 0.17677669529663687f;          // 32^-0.5
    const float* bF = biasF + (size_t)h * 4096 + lane * 4;
    const float* mF = maskF + (size_t)w * 4096 + lane * 4;
    #pragma unroll
    for (int mi = 0; mi < 2; mi++) {
        #pragma unroll
        for (int nt = 0; nt < 4; nt++) {
            const int gi = (wv * 2 + mi) * 4 + nt;
            const f32x4 bq = *(const f32x4*)(bF + gi * 256);
            const f32x4 mq = *(const f32x4*)(mF + gi * 256);
            const bool pad = (nt * 16 + l15) >= LW;
            #pragma unroll
            for (int r = 0; r < 4; r++) {
                const float v2 = fmaf(acc[mi][nt][r], scale, bq[r] + mq[r]);
                acc[mi][nt][r] = pad ? -1e30f : v2;
            }
        }
    }

    // ---- softmax over s (rows live within this wave) ----
    #pragma unroll
    for (int mi = 0; mi < 2; mi++) {
        #pragma unroll
        for (int r = 0; r < 4; r++) {
            float mx = fmaxf(fmaxf(acc[mi][0][r], acc[mi][1][r]),
                             fmaxf(acc[mi][2][r], acc[mi][3][r]));
            mx = fmaxf(mx, __shfl_xor(mx, 1));
            mx = fmaxf(mx, __shfl_xor(mx, 2));
            mx = fmaxf(mx, __shfl_xor(mx, 4));
            mx = fmaxf(mx, __shfl_xor(mx, 8));
            float sm = 0.f;
            #pragma unroll
            for (int nt = 0; nt < 4; nt++) {
                const float p = __expf(acc[mi][nt][r] - mx);
                acc[mi][nt][r] = p;
                sm += p;
            }
            sm += __shfl_xor(sm, 1);
            sm += __shfl_xor(sm, 2);
            sm += __shfl_xor(sm, 4);
            sm += __shfl_xor(sm, 8);
            const float inv = 1.0f / sm;
            #pragma unroll
            for (int nt = 0; nt < 4; nt++) acc[mi][nt][r] *= inv;
        }
    }

    // ---- pack this wave's P rows into hi/lo planes (swizzled) ----
    // Pad cols s>=49 hold exact 0 (exp(-1e30-mx)=0) -> contribute 0 in MFMA.
    #pragma unroll
    for (int mi = 0; mi < 2; mi++) {
        #pragma unroll
        for (int r = 0; r < 4; r++) {
            const int t = (wv * 2 + mi) * 16 + g4 * 4 + r;
            if (t < LW) {
                #pragma unroll
                for (int nt = 0; nt < 4; nt++) {
                    const int s = nt * 16 + l15;
                    const float p = acc[mi][nt][r];
                    const unsigned short ph = f2bf(p);
                    const unsigned short pl = f2bf(p - bf2f(ph));
                    // idx = t*64 + (((s>>3)^(t&7))<<3) + (s&7)
                    const unsigned idx = (unsigned)t * 64u
                        + ((((unsigned)s >> 3) ^ ((unsigned)t & 7u)) << 3)
                        + ((unsigned)s & 7u);
                    sHi[idx] = ph;
                    sLo[idx] = pl;
                }
            }
        }
    }

    // ---- issue K2 raw loads (c-tile wv); latency hides under attn+barrier ----
    float k2raw[2][8];
    {
        const int c = wv * 16 + l15;                   // c < 32 always
        #pragma unroll
        for (int ks = 0; ks < 2; ks++) {
            #pragma unroll
            for (int j = 0; j < 8; j++) {
                const int s  = ks * 32 + g4 * 8 + j;
                const int sc = s < LW ? s : (LW - 1);  // P at pad s is 0
                k2raw[ks][j] = kp[c * LW + sc];
            }
        }
    }

    // ---- attn writeout: direct from registers (clean when no spill) ----
    float* attn_base = attn_out + (size_t)bh * (LW * LW);
    #pragma unroll
    for (int mi = 0; mi < 2; mi++) {
        #pragma unroll
        for (int r = 0; r < 4; r++) {
            const int t = (wv * 2 + mi) * 16 + g4 * 4 + r;
            if (t < LW) {
                #pragma unroll
                for (int nt = 0; nt < 4; nt++) {
                    const int s = nt * 16 + l15;
                    if (s < LW) attn_base[t * LW + s] = acc[mi][nt][r];
                }
            }
        }
    }

    __syncthreads();   // pack (both waves) -> frag reads

    // ---- split K2 into frags ----
    Frag K2h[2], K2l[2];
    split8(k2raw[0], K2h[0], K2l[0]);
    split8(k2raw[1], K2h[1], K2l[1]);

    // ---- phase 3: score(c,t) = sum_s K(c,s) P(t,s); A-frags via b128 ----
    f32x4 acc2[4];
    #pragma unroll
    for (int nt = 0; nt < 4; nt++)
        #pragma unroll
        for (int r = 0; r < 4; r++) acc2[nt][r] = 0.f;

    #pragma unroll
    for (int ntt = 0; ntt < 4; ntt++) {
        const int t  = ntt * 16 + l15;
        const int tr = t < LW ? t : (LW - 1);          // clamped dead cols
        #pragma unroll
        for (int ks = 0; ks < 2; ks++) {
            const unsigned base = (unsigned)tr * 64u
                + (((unsigned)(ks * 4 + g4) ^ ((unsigned)tr & 7u)) << 3);
            Frag Ph, Pl;
            Ph.v = *(const s16x8*)&sHi[base];           // ds_read_b128
            Pl.v = *(const s16x8*)&sLo[base];           // ds_read_b128
            acc2[ntt] = MFMA16(K2h[ks].v, Ph.v, acc2[ntt]);
            acc2[ntt] = MFMA16(K2l[ks].v, Ph.v, acc2[ntt]);
            acc2[ntt] = MFMA16(K2h[ks].v, Pl.v, acc2[ntt]);
        }
    }

    // ---- score writeout: direct from registers ----
    float* scp = score_out + (size_t)bh * (32 * LW);
    #pragma unroll
    for (int ntt = 0; ntt < 4; ntt++) {
        const int t = ntt * 16 + l15;
        if (t < LW) {
            #pragma unroll
            for (int r = 0; r < 4; r++) {
                const int c = wv * 16 + g4 * 4 + r;
                scp[c * LW + t] = acc2[ntt][r];
            }
        }
    }
}

// ---------------- fallback (ws too small): VALU kernel ----------------------
__global__ __launch_bounds__(256, 4) void wa_fallback_kernel(
    const float* __restrict__ q, const float* __restrict__ k,
    const float* __restrict__ mask0, const float* __restrict__ table,
    const int* __restrict__ idx,
    float* __restrict__ score_out, float* __restrict__ attn_out)
{
    __shared__ float sPf[LW * LW];
    const int lane = threadIdx.x & 63;
    const int wv   = __builtin_amdgcn_readfirstlane((int)(threadIdx.x >> 6));
    const int bh   = blockIdx.x * 4 + wv;
    const int h    = bh & 7;
    const int w    = (bh >> 3) & 63;
    const int t    = lane;
    const int tc   = (t < LW) ? t : (LW - 1);

    const float* qp = q + (size_t)bh * (32 * LW);
    const float* kp = k + (size_t)bh * (32 * LW);

    float qreg[32];
    #pragma unroll
    for (int c = 0; c < 32; c++) qreg[c] = qp[c * LW + tc];

    float S[LW];
    #pragma unroll
    for (int s = 0; s < LW; s++) S[s] = 0.f;
    #pragma unroll
    for (int c = 0; c < 32; c++) {
        #pragma unroll
        for (int s = 0; s < LW; s++)
            S[s] = fmaf(qreg[c], kp[c * LW + s], S[s]);
    }

    const float scale = 0.17677669529663687f;
    const float* mrow = mask0 + (size_t)w * (LW * LW) + tc * LW;
    const int*   irow = idx + tc * LW;
    #pragma unroll
    for (int s = 0; s < LW; s++) {
        const float bm = table[irow[s] * NH + h] + mrow[s];
        S[s] = fmaf(S[s], scale, bm);
    }

    float m = S[0];
    #pragma unroll
    for (int s = 1; s < LW; s++) m = fmaxf(m, S[s]);
    float sum = 0.f;
    #pragma unroll
    for (int s = 0; s < LW; s++) { S[s] = __expf(S[s] - m); sum += S[s]; }
    const float invs = 1.0f / sum;
    #pragma unroll
    for (int s = 0; s < LW; s++) S[s] *= invs;

    float* attn_base = attn_out + (size_t)bh * (LW * LW);
    for (int turn = 0; turn < 4; turn++) {
        __syncthreads();
        if (turn == wv) {
            if (t < LW) {
                #pragma unroll
                for (int s = 0; s < LW; s++) sPf[t * LW + s] = S[s];
            }
            #pragma unroll
            for (int it = 0; it < 38; it++) {
                const int i = it * 64 + lane;
                if (i < LW * LW) attn_base[i] = sPf[i];
            }
        }
    }

    float* sc = score_out + (size_t)bh * (32 * LW);
    #pragma unroll
    for (int c = 0; c < 32; c++) {
        float a = 0.f;
        #pragma unroll
        for (int s = 0; s < LW; s++) a = fmaf(S[s], kp[c * LW + s], a);
        if (t < LW) sc[c * LW + t] = a;
    }
}

extern "C" void kernel_launch(void* const* d_in, const int* in_sizes, int n_in,
                              void* d_out, int out_size, void* d_ws, size_t ws_size,
                              hipStream_t stream) {
    const float* q     = (const float*)d_in[0];
    const float* k     = (const float*)d_in[1];
    // d_in[2] = v, unused: reference reassigns v = k
    const float* mask  = (const float*)d_in[3];
    const float* table = (const float*)d_in[4];
    const int*   idx   = (const int*)d_in[5];

    float* score_out = (float*)d_out;
    float* attn_out  = score_out + (size_t)2048 * 256 * 49;

    const size_t NBF = (size_t)8 * 4096;     // 32768 floats
    const size_t NMF = (size_t)64 * 4096;    // 262144 floats

    if (ws_size >= (NBF + NMF) * sizeof(float)) {
        float* biasF = (float*)d_ws;
        float* maskF = biasF + NBF;
        const int tot = (int)(NBF + NMF);
        prep_frag_kernel<<<(tot + 255) / 256, 256, 0, stream>>>(
            mask, table, idx, biasF, maskF);
        wa_mfma_kernel<<<16384, 128, 0, stream>>>(
            q, k, biasF, maskF, score_out, attn_out);
    } else {
        wa_fallback_kernel<<<4096, 256, 0, stream>>>(
            q, k, mask, table, idx, score_out, attn_out);
    }
}

// Round 7
// 493.752 us; speedup vs baseline: 1.0630x; 1.0630x over previous
//
#include <hip/hip_runtime.h>
#include <math.h>

// WindowAttention: B=2048, C=256, H=8, d_k=32, wh=ww=7 -> L=49, nW=64.
// Reference reassigns v = k. Outputs: score (2048*256*49) then attn
// (2048*8*49*49), fp32, concatenated in d_out.
//
// MFMA design, R7: 2 waves per (b,h), 128-thread block.
//
// R6 lesson (counter-proven): per-wave time was dominated by serialized
// global-load chains (compiler schedules loads just-in-time at min regs),
// so halving compute per wave didn't reduce per-wave latency. R7 fixes:
//  (a) PREFETCH: all 48 raw loads/wave (Q-half, K1-half, K2) issued
//      back-to-back in the prologue -> one latency exposure, not ~5.
//  (b) K1 SHARING: wave wv loads+splits only K-tiles {2wv,2wv+1}, stages
//      hi/lo frags in LDS; both waves read all 4 tiles via ds_read_b128.
//      Halves K1 traffic + split VALU per block.
//  (c) LDS reuse: K planes (8KB) and P planes (12.25KB) share one buffer
//      (barrier-protected) -> 12.25KB/block, 12 blocks/CU ceiling.
//  (d) attn stores issued AFTER the pack barrier so they overlap phase-3
//      compute instead of being drained by the barrier's vmcnt(0).
//
// Spill discipline (R2-R4 counter-proven): peak live ~110 regs under the
// launch_bounds(128,4) cap of 128; WRITE_SIZE inflation is the tripwire.
//
//  phase1: S = Q^T K via mfma_f32_16x16x32_bf16, RNE hi/lo bf16 split,
//          3 passes -> ~fp32 accuracy (absmax 0.0078).
//  softmax on C-frag layout (col=lane&15, row=(lane>>4)*4+reg), shfl_xor.
//  phase3: score = K P^T from LDS-packed P planes (16B-slot XOR swizzle).
//  bias+mask pre-expanded into fragment order -> coalesced f32x4 loads.

#define LW 49
#define NH 8

typedef short s16x8 __attribute__((ext_vector_type(8)));
typedef float f32x4 __attribute__((ext_vector_type(4)));

union Frag { s16x8 v; unsigned short u[8]; };

__device__ __forceinline__ unsigned short f2bf(float x) {
    unsigned u = __float_as_uint(x);
    u += 0x7FFFu + ((u >> 16) & 1u);          // round-to-nearest-even
    return (unsigned short)(u >> 16);
}
__device__ __forceinline__ float bf2f(unsigned short h) {
    return __uint_as_float(((unsigned)h) << 16);
}
// RNE split: hi = bf16_rne(x); lo = bf16_rne(x - hi).
__device__ __forceinline__ void split8(const float* xf, Frag& hi, Frag& lo) {
    #pragma unroll
    for (int j = 0; j < 8; j++) {
        const unsigned short hb = f2bf(xf[j]);
        hi.u[j] = hb;
        lo.u[j] = f2bf(xf[j] - bf2f(hb));
    }
}

#define MFMA16(A, B, C) __builtin_amdgcn_mfma_f32_16x16x32_bf16((A), (B), (C), 0, 0, 0)

// ---------------- prep: bias & mask expanded into C-fragment order ----------
__global__ __launch_bounds__(256) void prep_frag_kernel(
    const float* __restrict__ mask, const float* __restrict__ table,
    const int* __restrict__ idx,
    float* __restrict__ biasF, float* __restrict__ maskF)
{
    const int i = blockIdx.x * 256 + threadIdx.x;
    const int NBF = 8 * 4096;        // 32768
    const int NMF = 64 * 4096;       // 262144
    if (i < NBF) {
        const int h = i >> 12, rem = i & 4095;
        const int gi = rem >> 8, lane = (rem >> 2) & 63, r = rem & 3;
        const int mt = gi >> 2, nt = gi & 3;
        const int t = mt * 16 + (lane >> 4) * 4 + r;
        const int s = nt * 16 + (lane & 15);
        biasF[i] = (t < LW && s < LW) ? table[idx[t * LW + s] * NH + h] : 0.f;
    } else if (i < NBF + NMF) {
        const int j = i - NBF;
        const int w2 = j >> 12, rem = j & 4095;
        const int gi = rem >> 8, lane = (rem >> 2) & 63, r = rem & 3;
        const int mt = gi >> 2, nt = gi & 3;
        const int t = mt * 16 + (lane >> 4) * 4 + r;
        const int s = nt * 16 + (lane & 15);
        maskF[j] = (t < LW && s < LW) ? mask[w2 * (LW * LW) + t * LW + s] : 0.f;
    }
}

// ---------------- main: 2 waves per (b,h) -----------------------------------
__global__ __launch_bounds__(128, 4) void wa_mfma_kernel(
    const float* __restrict__ q, const float* __restrict__ k,
    const float* __restrict__ biasF, const float* __restrict__ maskF,
    float* __restrict__ score_out, float* __restrict__ attn_out)
{
    // Shared buffer, 12544 B, two overlapping uses (barrier-protected):
    //  K stage:  kHi = sB[0..2047]  (tile nt at nt*512 + lane*8, 8 u16/lane)
    //            kLo = sB[2048..4095]
    //  P planes: pHi = sB[0..3135]  (t*64 + swizzled s)
    //            pLo = sB[3136..6271]
    __shared__ __align__(16) unsigned short sB[6272];

    const int wv   = __builtin_amdgcn_readfirstlane((int)(threadIdx.x >> 6));
    const int bh   = blockIdx.x;
    const int h    = bh & 7;
    const int w    = (bh >> 3) & 63;
    const int lane = threadIdx.x & 63;
    const int l15  = lane & 15;
    const int g4   = lane >> 4;

    const float* qp = q + (size_t)bh * (32 * LW);
    const float* kp = k + (size_t)bh * (32 * LW);

    // ==== prologue: issue ALL raw loads back-to-back (one latency hit) ====
    float k1raw[2][8], qraw[2][8], k2raw[2][8];
    #pragma unroll
    for (int ki = 0; ki < 2; ki++) {               // my half of K cols
        const int s  = (wv * 2 + ki) * 16 + l15;
        const int sc = s < LW ? s : (LW - 1);
        #pragma unroll
        for (int j = 0; j < 8; j++) k1raw[ki][j] = kp[(g4 * 8 + j) * LW + sc];
    }
    #pragma unroll
    for (int mi = 0; mi < 2; mi++) {               // my 2 Q row-tiles
        const int t  = (wv * 2 + mi) * 16 + l15;
        const int tc = t < LW ? t : (LW - 1);
        #pragma unroll
        for (int j = 0; j < 8; j++) qraw[mi][j] = qp[(g4 * 8 + j) * LW + tc];
    }
    {                                              // my K2 c-tile (phase 3)
        const int c = wv * 16 + l15;               // c < 32 always
        #pragma unroll
        for (int ks = 0; ks < 2; ks++)
            #pragma unroll
            for (int j = 0; j < 8; j++) {
                const int s  = ks * 32 + g4 * 8 + j;
                const int sc = s < LW ? s : (LW - 1);   // P at pad s is 0
                k2raw[ks][j] = kp[c * LW + sc];
            }
    }

    // ==== split my K1 half -> LDS frag planes (b128 writes) ====
    #pragma unroll
    for (int ki = 0; ki < 2; ki++) {
        const int nt = wv * 2 + ki;
        Frag Kh, Kl;
        split8(k1raw[ki], Kh, Kl);
        *(s16x8*)&sB[nt * 512 + lane * 8]        = Kh.v;
        *(s16x8*)&sB[2048 + nt * 512 + lane * 8] = Kl.v;
    }

    // ==== split Q -> frags ====
    Frag Qh[2], Ql[2];
    split8(qraw[0], Qh[0], Ql[0]);
    split8(qraw[1], Qh[1], Ql[1]);

    __syncthreads();   // #1: K frags staged

    // ==== phase 1: S rows of this wave (3-pass split bf16) ====
    f32x4 acc[2][4];
    #pragma unroll
    for (int mi = 0; mi < 2; mi++)
        #pragma unroll
        for (int nt = 0; nt < 4; nt++)
            #pragma unroll
            for (int r = 0; r < 4; r++) acc[mi][nt][r] = 0.f;

    #pragma unroll
    for (int nt = 0; nt < 4; nt++) {
        Frag Kh, Kl;
        Kh.v = *(const s16x8*)&sB[nt * 512 + lane * 8];
        Kl.v = *(const s16x8*)&sB[2048 + nt * 512 + lane * 8];
        #pragma unroll
        for (int mi = 0; mi < 2; mi++) {
            acc[mi][nt] = MFMA16(Qh[mi].v, Kh.v, acc[mi][nt]);
            acc[mi][nt] = MFMA16(Ql[mi].v, Kh.v, acc[mi][nt]);
            acc[mi][nt] = MFMA16(Qh[mi].v, Kl.v, acc[mi][nt]);
        }
    }

    // ==== scale + bias + mask (frag-ordered tables); pad cols -> -inf ====
    const float scale = 0.17677669529663687f;          // 32^-0.5
    const float* bF = biasF + (size_t)h * 4096 + lane * 4;
    const float* mF = maskF + (size_t)w * 4096 + lane * 4;
    #pragma unroll
    for (int mi = 0; mi < 2; mi++) {
        #pragma unroll
        for (int nt = 0; nt < 4; nt++) {
            const int gi = (wv * 2 + mi) * 4 + nt;
            const f32x4 bq = *(const f32x4*)(bF + gi * 256);
            const f32x4 mq = *(const f32x4*)(mF + gi * 256);
            const bool pad = (nt * 16 + l15) >= LW;
            #pragma unroll
            for (int r = 0; r < 4; r++) {
                const float v2 = fmaf(acc[mi][nt][r], scale, bq[r] + mq[r]);
                acc[mi][nt][r] = pad ? -1e30f : v2;
            }
        }
    }

    // ==== softmax over s (rows live within this wave) ====
    #pragma unroll
    for (int mi = 0; mi < 2; mi++) {
        #pragma unroll
        for (int r = 0; r < 4; r++) {
            float mx = fmaxf(fmaxf(acc[mi][0][r], acc[mi][1][r]),
                             fmaxf(acc[mi][2][r], acc[mi][3][r]));
            mx = fmaxf(mx, __shfl_xor(mx, 1));
            mx = fmaxf(mx, __shfl_xor(mx, 2));
            mx = fmaxf(mx, __shfl_xor(mx, 4));
            mx = fmaxf(mx, __shfl_xor(mx, 8));
            float sm = 0.f;
            #pragma unroll
            for (int nt = 0; nt < 4; nt++) {
                const float p = __expf(acc[mi][nt][r] - mx);
                acc[mi][nt][r] = p;
                sm += p;
            }
            sm += __shfl_xor(sm, 1);
            sm += __shfl_xor(sm, 2);
            sm += __shfl_xor(sm, 4);
            sm += __shfl_xor(sm, 8);
            const float inv = 1.0f / sm;
            #pragma unroll
            for (int nt = 0; nt < 4; nt++) acc[mi][nt][r] *= inv;
        }
    }

    __syncthreads();   // #2: all K-LDS reads done; safe to overwrite with P

    // ==== pack this wave's P rows into hi/lo planes (swizzled) ====
    // Pad cols s>=49 hold exact 0 (exp(-1e30-mx)=0) -> contribute 0 in MFMA.
    #pragma unroll
    for (int mi = 0; mi < 2; mi++) {
        #pragma unroll
        for (int r = 0; r < 4; r++) {
            const int t = (wv * 2 + mi) * 16 + g4 * 4 + r;
            if (t < LW) {
                #pragma unroll
                for (int nt = 0; nt < 4; nt++) {
                    const int s = nt * 16 + l15;
                    const float p = acc[mi][nt][r];
                    const unsigned short ph = f2bf(p);
                    const unsigned short pl = f2bf(p - bf2f(ph));
                    const unsigned idx = (unsigned)t * 64u
                        + ((((unsigned)s >> 3) ^ ((unsigned)t & 7u)) << 3)
                        + ((unsigned)s & 7u);
                    sB[idx]        = ph;
                    sB[3136 + idx] = pl;
                }
            }
        }
    }

    __syncthreads();   // #3: P staged (both waves)

    // ==== attn writeout now (stores overlap phase-3 compute) ====
    float* attn_base = attn_out + (size_t)bh * (LW * LW);
    #pragma unroll
    for (int mi = 0; mi < 2; mi++) {
        #pragma unroll
        for (int r = 0; r < 4; r++) {
            const int t = (wv * 2 + mi) * 16 + g4 * 4 + r;
            if (t < LW) {
                #pragma unroll
                for (int nt = 0; nt < 4; nt++) {
                    const int s = nt * 16 + l15;
                    if (s < LW) attn_base[t * LW + s] = acc[mi][nt][r];
                }
            }
        }
    }

    // ==== split K2 into frags (loads long since landed) ====
    Frag K2h[2], K2l[2];
    split8(k2raw[0], K2h[0], K2l[0]);
    split8(k2raw[1], K2h[1], K2l[1]);

    // ==== phase 3: score(c,t) = sum_s K(c,s) P(t,s); A-frags via b128 ====
    f32x4 acc2[4];
    #pragma unroll
    for (int nt = 0; nt < 4; nt++)
        #pragma unroll
        for (int r = 0; r < 4; r++) acc2[nt][r] = 0.f;

    #pragma unroll
    for (int ntt = 0; ntt < 4; ntt++) {
        const int t  = ntt * 16 + l15;
        const int tr = t < LW ? t : (LW - 1);          // clamped dead cols
        #pragma unroll
        for (int ks = 0; ks < 2; ks++) {
            const unsigned base = (unsigned)tr * 64u
                + (((unsigned)(ks * 4 + g4) ^ ((unsigned)tr & 7u)) << 3);
            Frag Ph, Pl;
            Ph.v = *(const s16x8*)&sB[base];            // ds_read_b128
            Pl.v = *(const s16x8*)&sB[3136 + base];     // ds_read_b128
            acc2[ntt] = MFMA16(K2h[ks].v, Ph.v, acc2[ntt]);
            acc2[ntt] = MFMA16(K2l[ks].v, Ph.v, acc2[ntt]);
            acc2[ntt] = MFMA16(K2h[ks].v, Pl.v, acc2[ntt]);
        }
    }

    // ==== score writeout: direct from registers ====
    float* scp = score_out + (size_t)bh * (32 * LW);
    #pragma unroll
    for (int ntt = 0; ntt < 4; ntt++) {
        const int t = ntt * 16 + l15;
        if (t < LW) {
            #pragma unroll
            for (int r = 0; r < 4; r++) {
                const int c = wv * 16 + g4 * 4 + r;
                scp[c * LW + t] = acc2[ntt][r];
            }
        }
    }
}

// ---------------- fallback (ws too small): VALU kernel ----------------------
__global__ __launch_bounds__(256, 4) void wa_fallback_kernel(
    const float* __restrict__ q, const float* __restrict__ k,
    const float* __restrict__ mask0, const float* __restrict__ table,
    const int* __restrict__ idx,
    float* __restrict__ score_out, float* __restrict__ attn_out)
{
    __shared__ float sPf[LW * LW];
    const int lane = threadIdx.x & 63;
    const int wv   = __builtin_amdgcn_readfirstlane((int)(threadIdx.x >> 6));
    const int bh   = blockIdx.x * 4 + wv;
    const int h    = bh & 7;
    const int w    = (bh >> 3) & 63;
    const int t    = lane;
    const int tc   = (t < LW) ? t : (LW - 1);

    const float* qp = q + (size_t)bh * (32 * LW);
    const float* kp = k + (size_t)bh * (32 * LW);

    float qreg[32];
    #pragma unroll
    for (int c = 0; c < 32; c++) qreg[c] = qp[c * LW + tc];

    float S[LW];
    #pragma unroll
    for (int s = 0; s < LW; s++) S[s] = 0.f;
    #pragma unroll
    for (int c = 0; c < 32; c++) {
        #pragma unroll
        for (int s = 0; s < LW; s++)
            S[s] = fmaf(qreg[c], kp[c * LW + s], S[s]);
    }

    const float scale = 0.17677669529663687f;
    const float* mrow = mask0 + (size_t)w * (LW * LW) + tc * LW;
    const int*   irow = idx + tc * LW;
    #pragma unroll
    for (int s = 0; s < LW; s++) {
        const float bm = table[irow[s] * NH + h] + mrow[s];
        S[s] = fmaf(S[s], scale, bm);
    }

    float m = S[0];
    #pragma unroll
    for (int s = 1; s < LW; s++) m = fmaxf(m, S[s]);
    float sum = 0.f;
    #pragma unroll
    for (int s = 0; s < LW; s++) { S[s] = __expf(S[s] - m); sum += S[s]; }
    const float invs = 1.0f / sum;
    #pragma unroll
    for (int s = 0; s < LW; s++) S[s] *= invs;

    float* attn_base = attn_out + (size_t)bh * (LW * LW);
    for (int turn = 0; turn < 4; turn++) {
        __syncthreads();
        if (turn == wv) {
            if (t < LW) {
                #pragma unroll
                for (int s = 0; s < LW; s++) sPf[t * LW + s] = S[s];
            }
            #pragma unroll
            for (int it = 0; it < 38; it++) {
                const int i = it * 64 + lane;
                if (i < LW * LW) attn_base[i] = sPf[i];
            }
        }
    }

    float* sc = score_out + (size_t)bh * (32 * LW);
    #pragma unroll
    for (int c = 0; c < 32; c++) {
        float a = 0.f;
        #pragma unroll
        for (int s = 0; s < LW; s++) a = fmaf(S[s], kp[c * LW + s], a);
        if (t < LW) sc[c * LW + t] = a;
    }
}

extern "C" void kernel_launch(void* const* d_in, const int* in_sizes, int n_in,
                              void* d_out, int out_size, void* d_ws, size_t ws_size,
                              hipStream_t stream) {
    const float* q     = (const float*)d_in[0];
    const float* k     = (const float*)d_in[1];
    // d_in[2] = v, unused: reference reassigns v = k
    const float* mask  = (const float*)d_in[3];
    const float* table = (const float*)d_in[4];
    const int*   idx   = (const int*)d_in[5];

    float* score_out = (float*)d_out;
    float* attn_out  = score_out + (size_t)2048 * 256 * 49;

    const size_t NBF = (size_t)8 * 4096;     // 32768 floats
    const size_t NMF = (size_t)64 * 4096;    // 262144 floats

    if (ws_size >= (NBF + NMF) * sizeof(float)) {
        float* biasF = (float*)d_ws;
        float* maskF = biasF + NBF;
        const int tot = (int)(NBF + NMF);
        prep_frag_kernel<<<(tot + 255) / 256, 256, 0, stream>>>(
            mask, table, idx, biasF, maskF);
        wa_mfma_kernel<<<16384, 128, 0, stream>>>(
            q, k, biasF, maskF, score_out, attn_out);
    } else {
        wa_fallback_kernel<<<4096, 256, 0, stream>>>(
            q, k, mask, table, idx, score_out, attn_out);
    }
}